// Round 9
// baseline (1566.634 us; speedup 1.0000x reference)
//
#include <hip/hip_runtime.h>

#define NN 100000
#define NE 3200000
#define HID 64
#define NPB 128                         // nodes per bucket (dstlocal = dst & 127)
#define NB  ((NN + NPB - 1) / NPB)      // 782 buckets
#define CHUNK 4096                      // edges per hist/scatter workgroup
#define NCH ((NE + CHUNK - 1) / CHUNK)  // 782 chunks
#define APITCH 68                       // fp32 agg row pitch: 272 B (16B-aligned, <=2-way banks)
#define BPITCH 136                      // f16 Bt row pitch: 272 B

typedef _Float16 half8 __attribute__((ext_vector_type(8)));
typedef float f32x4 __attribute__((ext_vector_type(4)));

// ws layout (4B words), ~27.2 MB:
//  [0, 2*NE)    rec (int2: .x = src | dstlocal<<20, .y = ew bits), bucket-sorted
//  then sx[2NN] (float2: s1,x), p[NN], r[NN], ghist[NB], gbase[NB], gcur[NB]

// -------- global histogram over dst buckets --------
__global__ __launch_bounds__(256) void k_hist(const int* __restrict__ dst,
                                              int* __restrict__ ghist) {
    __shared__ int sh[NB];
    for (int j = threadIdx.x; j < NB; j += 256) sh[j] = 0;
    __syncthreads();
    const long long b0 = (long long)blockIdx.x * CHUNK;
    #pragma unroll
    for (int k = 0; k < CHUNK / 256; ++k) {
        long long e = b0 + k * 256 + threadIdx.x;
        if (e < NE) atomicAdd(&sh[dst[e] >> 7], 1);
    }
    __syncthreads();
    for (int j = threadIdx.x; j < NB; j += 256) {
        int c = sh[j];
        if (c) atomicAdd(&ghist[j], c);
    }
}

// -------- exclusive scan of NB bucket counts (single WG) --------
__global__ void k_scan(const int* __restrict__ ghist, int* __restrict__ gbase,
                       int* __restrict__ gcur) {
    __shared__ int sh[1024];
    const int tid = threadIdx.x;
    int v = (tid < NB) ? ghist[tid] : 0;
    sh[tid] = v;
    __syncthreads();
    #pragma unroll
    for (int off = 1; off < 1024; off <<= 1) {
        int t = (tid >= off) ? sh[tid - off] : 0;
        __syncthreads();
        sh[tid] += t;
        __syncthreads();
    }
    if (tid < NB) {
        int b = sh[tid] - v;
        gbase[tid] = b;
        gcur[tid] = b;
    }
}

// -------- bucketed scatter: LDS-staged, one reservation atomic per (WG,bucket) --------
__global__ __launch_bounds__(256) void k_scatter(const int* __restrict__ src,
                                                 const int* __restrict__ dst,
                                                 const float* __restrict__ ew,
                                                 int* __restrict__ gcur,
                                                 int2* __restrict__ rec) {
    __shared__ int sh_px[CHUNK];
    __shared__ int sh_w[CHUNK];
    __shared__ unsigned short sh_b[CHUNK];
    __shared__ int sh_cnt[NB];
    __shared__ int sh_base[NB];
    for (int j = threadIdx.x; j < NB; j += 256) sh_cnt[j] = 0;
    __syncthreads();
    const long long b0 = (long long)blockIdx.x * CHUNK;
    #pragma unroll
    for (int k = 0; k < CHUNK / 256; ++k) {
        int idx = k * 256 + threadIdx.x;
        long long e = b0 + idx;
        if (e < NE) {
            int d = dst[e];
            int b = d >> 7;
            sh_px[idx] = src[e] | ((d & 127) << 20);   // src < 2^20
            sh_w[idx] = __float_as_int(ew[e]);
            sh_b[idx] = (unsigned short)b;
            atomicAdd(&sh_cnt[b], 1);
        }
    }
    __syncthreads();
    for (int j = threadIdx.x; j < NB; j += 256) {
        int c = sh_cnt[j];
        sh_base[j] = c ? atomicAdd(&gcur[j], c) : 0;
        sh_cnt[j] = 0;                                  // reuse as running offset
    }
    __syncthreads();
    #pragma unroll
    for (int k = 0; k < CHUNK / 256; ++k) {
        int idx = k * 256 + threadIdx.x;
        long long e = b0 + idx;
        if (e < NE) {
            int b = sh_b[idx];
            int off = atomicAdd(&sh_cnt[b], 1);
            rec[sh_base[b] + off] = make_int2(sh_px[idx], sh_w[idx]);
        }
    }
}

// -------- bucketed scalar aggregation: sx[i] = (s1[i], x[i]) --------
__global__ __launch_bounds__(256) void k_s1(const int* __restrict__ gbase,
                                            const int* __restrict__ ghist,
                                            const int2* __restrict__ rec,
                                            const float* __restrict__ x,
                                            float2* __restrict__ sx) {
    __shared__ float loc[NPB];
    if (threadIdx.x < NPB) loc[threadIdx.x] = 0.f;
    __syncthreads();
    const int b = blockIdx.x;
    const int beg = gbase[b], cnt = ghist[b];
    for (int t = threadIdx.x; t < cnt; t += 256) {
        int2 rc = rec[beg + t];
        atomicAdd(&loc[rc.x >> 20], __int_as_float(rc.y) * x[rc.x & 0xFFFFF]);
    }
    __syncthreads();
    int i = b * NPB + threadIdx.x;
    if (threadIdx.x < NPB && i < NN) sx[i] = make_float2(loc[threadIdx.x], x[i]);
}

// -------- mega: bucket edge-agg into LDS + in-block f16 MFMA node-GEMM + p/r --------
__global__ __launch_bounds__(256) void k_mega(
        const int* __restrict__ gbase, const int* __restrict__ ghist,
        const int2* __restrict__ rec, const float2* __restrict__ sx,
        const float* __restrict__ W1_rel, const float* __restrict__ W1_root,
        const float* __restrict__ b1,
        const float* __restrict__ W2_rel, const float* __restrict__ b2,
        const float* __restrict__ W2_root,
        const float* __restrict__ W3_rel, const float* __restrict__ W3_root,
        float* __restrict__ p, float* __restrict__ r) {
    __shared__ float agg[NPB * APITCH];       // 34816 B, fp32 aggregate
    __shared__ _Float16 Bt[HID * BPITCH];     // 17408 B, [n][k]: k<64 W2rel, k>=64 W2root
    __shared__ float2 sxl[NPB];               // 1024 B

    const int tid = threadIdx.x;
    const int f = tid & 63;
    const int wv = tid >> 6;
    const int b = blockIdx.x;
    const int gi0 = b * NPB;

    for (int j = tid; j < NPB * APITCH; j += 256) agg[j] = 0.f;
    for (int idx = tid; idx < HID * HID; idx += 256) {
        int k = idx >> 6, n = idx & 63;
        Bt[n * BPITCH + k]       = (_Float16)W2_rel[idx];
        Bt[n * BPITCH + HID + k] = (_Float16)W2_root[idx];
    }
    if (tid < NPB) {
        int gi = gi0 + tid;
        sxl[tid] = (gi < NN) ? sx[gi] : make_float2(0.f, 0.f);
    }
    const float w1r = W1_rel[f], w1t = W1_root[f], b1f = b1[f];
    __syncthreads();

    // ---- edge loop: R6-proven 8-wide shape, ds_add into agg (2-way banks = free) ----
    const int beg = gbase[b], cnt = ghist[b];
    const int qs = (cnt + 3) >> 2;
    int e = beg + wv * qs;
    const int eend = min(beg + cnt, e + qs);
    for (; e + 8 <= eend; e += 8) {
        int2 q0 = rec[e],     q1 = rec[e + 1], q2 = rec[e + 2], q3 = rec[e + 3];
        int2 q4 = rec[e + 4], q5 = rec[e + 5], q6 = rec[e + 6], q7 = rec[e + 7];
        float2 v0 = sx[q0.x & 0xFFFFF];
        float2 v1 = sx[q1.x & 0xFFFFF];
        float2 v2 = sx[q2.x & 0xFFFFF];
        float2 v3 = sx[q3.x & 0xFFFFF];
        float2 v4 = sx[q4.x & 0xFFFFF];
        float2 v5 = sx[q5.x & 0xFFFFF];
        float2 v6 = sx[q6.x & 0xFFFFF];
        float2 v7 = sx[q7.x & 0xFFFFF];
        atomicAdd(&agg[(q0.x >> 20) * APITCH + f],
                  __int_as_float(q0.y) * fmaxf(0.f, fmaf(v0.x, w1r, fmaf(v0.y, w1t, b1f))));
        atomicAdd(&agg[(q1.x >> 20) * APITCH + f],
                  __int_as_float(q1.y) * fmaxf(0.f, fmaf(v1.x, w1r, fmaf(v1.y, w1t, b1f))));
        atomicAdd(&agg[(q2.x >> 20) * APITCH + f],
                  __int_as_float(q2.y) * fmaxf(0.f, fmaf(v2.x, w1r, fmaf(v2.y, w1t, b1f))));
        atomicAdd(&agg[(q3.x >> 20) * APITCH + f],
                  __int_as_float(q3.y) * fmaxf(0.f, fmaf(v3.x, w1r, fmaf(v3.y, w1t, b1f))));
        atomicAdd(&agg[(q4.x >> 20) * APITCH + f],
                  __int_as_float(q4.y) * fmaxf(0.f, fmaf(v4.x, w1r, fmaf(v4.y, w1t, b1f))));
        atomicAdd(&agg[(q5.x >> 20) * APITCH + f],
                  __int_as_float(q5.y) * fmaxf(0.f, fmaf(v5.x, w1r, fmaf(v5.y, w1t, b1f))));
        atomicAdd(&agg[(q6.x >> 20) * APITCH + f],
                  __int_as_float(q6.y) * fmaxf(0.f, fmaf(v6.x, w1r, fmaf(v6.y, w1t, b1f))));
        atomicAdd(&agg[(q7.x >> 20) * APITCH + f],
                  __int_as_float(q7.y) * fmaxf(0.f, fmaf(v7.x, w1r, fmaf(v7.y, w1t, b1f))));
    }
    for (; e < eend; ++e) {
        int2 q0 = rec[e];
        float2 v0 = sx[q0.x & 0xFFFFF];
        atomicAdd(&agg[(q0.x >> 20) * APITCH + f],
                  __int_as_float(q0.y) * fmaxf(0.f, fmaf(v0.x, w1r, fmaf(v0.y, w1t, b1f))));
    }
    __syncthreads();

    // ---- MFMA: O[128,64] = [AGG | H1] @ [W2rel ; W2root], f16 in / fp32 acc ----
    // A-layout: A[m=lane&15][k=quad*8+j]; C/D: col=lane&15, row=quad*4+reg (HW-verified)
    const int lane = tid & 63;
    const int m16 = lane & 15;
    const int quad = lane >> 4;
    f32x4 acc[2][4];
    #pragma unroll
    for (int a_ = 0; a_ < 2; ++a_)
        #pragma unroll
        for (int c_ = 0; c_ < 4; ++c_)
            acc[a_][c_] = (f32x4){0.f, 0.f, 0.f, 0.f};

    const float2 sm0 = sxl[(2 * wv + 0) * 16 + m16];
    const float2 sm1 = sxl[(2 * wv + 1) * 16 + m16];

    #pragma unroll
    for (int kt = 0; kt < 4; ++kt) {
        const int kk = kt * 32;
        half8 a0, a1;
        if (kt < 2) {
            // A rows from fp32 agg LDS, cvt on the fly
            const float* pa0 = &agg[((2 * wv + 0) * 16 + m16) * APITCH + kk + quad * 8];
            const float* pa1 = &agg[((2 * wv + 1) * 16 + m16) * APITCH + kk + quad * 8];
            #pragma unroll
            for (int j = 0; j < 8; ++j) {
                a0[j] = (_Float16)pa0[j];
                a1[j] = (_Float16)pa1[j];
            }
        } else {
            // A cols 64..127 = h1, synthesized from sx (2 FMA + relu per element)
            const int fk0 = (kt - 2) * 32 + quad * 8;
            #pragma unroll
            for (int j = 0; j < 8; ++j) {
                const float wr = W1_rel[fk0 + j], wt = W1_root[fk0 + j], bb = b1[fk0 + j];
                a0[j] = (_Float16)fmaxf(0.f, fmaf(sm0.x, wr, fmaf(sm0.y, wt, bb)));
                a1[j] = (_Float16)fmaxf(0.f, fmaf(sm1.x, wr, fmaf(sm1.y, wt, bb)));
            }
        }
        #pragma unroll
        for (int ct = 0; ct < 4; ++ct) {
            const half8 bfrag = *(const half8*)&Bt[(ct * 16 + m16) * BPITCH + kk + quad * 8];
            acc[0][ct] = __builtin_amdgcn_mfma_f32_16x16x32_f16(a0, bfrag, acc[0][ct], 0, 0, 0);
            acc[1][ct] = __builtin_amdgcn_mfma_f32_16x16x32_f16(a1, bfrag, acc[1][ct], 0, 0, 0);
        }
    }

    // ---- epilogue: h2 = relu(o + b2); p = h2.W3rel, r = h2.W3root ----
    float b2c[4], w3rc[4], w3tc[4];
    #pragma unroll
    for (int ct = 0; ct < 4; ++ct) {
        const int col = ct * 16 + m16;
        b2c[ct] = b2[col]; w3rc[ct] = W3_rel[col]; w3tc[ct] = W3_root[col];
    }
    #pragma unroll
    for (int rt = 0; rt < 2; ++rt) {
        float pv[4] = {0.f, 0.f, 0.f, 0.f}, rv[4] = {0.f, 0.f, 0.f, 0.f};
        #pragma unroll
        for (int ct = 0; ct < 4; ++ct) {
            #pragma unroll
            for (int reg = 0; reg < 4; ++reg) {
                const float h2 = fmaxf(0.f, acc[rt][ct][reg] + b2c[ct]);
                pv[reg] = fmaf(h2, w3rc[ct], pv[reg]);
                rv[reg] = fmaf(h2, w3tc[ct], rv[reg]);
            }
        }
        #pragma unroll
        for (int reg = 0; reg < 4; ++reg) {
            #pragma unroll
            for (int msk = 1; msk < 16; msk <<= 1) {
                pv[reg] += __shfl_xor(pv[reg], msk, 64);
                rv[reg] += __shfl_xor(rv[reg], msk, 64);
            }
        }
        if (m16 == 0) {
            #pragma unroll
            for (int reg = 0; reg < 4; ++reg) {
                const int gi = gi0 + (2 * wv + rt) * 16 + quad * 4 + reg;
                if (gi < NN) { p[gi] = pv[reg]; r[gi] = rv[reg]; }
            }
        }
    }
}

// -------- bucketed output: out = seg_sum(w * p[src]) + r + b3 --------
__global__ __launch_bounds__(256) void k_out(const int* __restrict__ gbase,
                                             const int* __restrict__ ghist,
                                             const int2* __restrict__ rec,
                                             const float* __restrict__ pp,
                                             const float* __restrict__ rr,
                                             const float* __restrict__ b3,
                                             float* __restrict__ out) {
    __shared__ float loc[NPB];
    if (threadIdx.x < NPB) loc[threadIdx.x] = 0.f;
    __syncthreads();
    const int b = blockIdx.x;
    const int beg = gbase[b], cnt = ghist[b];
    for (int t = threadIdx.x; t < cnt; t += 256) {
        int2 rc = rec[beg + t];
        atomicAdd(&loc[rc.x >> 20], __int_as_float(rc.y) * pp[rc.x & 0xFFFFF]);
    }
    __syncthreads();
    int i = b * NPB + threadIdx.x;
    if (threadIdx.x < NPB && i < NN) out[i] = loc[threadIdx.x] + rr[i] + b3[0];
}

extern "C" void kernel_launch(void* const* d_in, const int* in_sizes, int n_in,
                              void* d_out, int out_size, void* d_ws, size_t ws_size,
                              hipStream_t stream) {
    const float* x       = (const float*)d_in[0];
    const int*   ei      = (const int*)  d_in[1];
    const float* ew      = (const float*)d_in[2];
    const float* W1_rel  = (const float*)d_in[3];
    const float* b1      = (const float*)d_in[4];
    const float* W1_root = (const float*)d_in[5];
    const float* W2_rel  = (const float*)d_in[6];
    const float* b2      = (const float*)d_in[7];
    const float* W2_root = (const float*)d_in[8];
    const float* W3_rel  = (const float*)d_in[9];
    const float* b3      = (const float*)d_in[10];
    const float* W3_root = (const float*)d_in[11];

    const int* src = ei;
    const int* dst = ei + NE;

    int2*   rec   = (int2*)d_ws;
    float2* sx    = (float2*)((int*)d_ws + 2 * (size_t)NE);
    float*  p     = (float*)(sx + NN);
    float*  r     = p + NN;
    int*    ghist = (int*)(r + NN);
    int*    gbase = ghist + NB;
    int*    gcur  = gbase + NB;

    hipMemsetAsync(ghist, 0, NB * sizeof(int), stream);

    k_hist<<<NCH, 256, 0, stream>>>(dst, ghist);
    k_scan<<<1, 1024, 0, stream>>>(ghist, gbase, gcur);
    k_scatter<<<NCH, 256, 0, stream>>>(src, dst, ew, gcur, rec);
    k_s1<<<NB, 256, 0, stream>>>(gbase, ghist, rec, x, sx);
    k_mega<<<NB, 256, 0, stream>>>(gbase, ghist, rec, sx,
                                   W1_rel, W1_root, b1,
                                   W2_rel, b2, W2_root,
                                   W3_rel, W3_root, p, r);
    k_out<<<NB, 256, 0, stream>>>(gbase, ghist, rec, p, r, b3, (float*)d_out);
}

// Round 10
// 494.633 us; speedup vs baseline: 3.1673x; 3.1673x over previous
//
#include <hip/hip_runtime.h>

#define NN 100000
#define NE 3200000
#define HID 64
#define NPB 128                         // nodes per bucket (dstlocal = dst & 127)
#define NB  ((NN + NPB - 1) / NPB)      // 782 buckets
#define CHUNK 4096                      // edges per hist/scatter workgroup
#define NCH ((NE + CHUNK - 1) / CHUNK)  // 782 chunks
#define CAP 5632                        // per-bucket record capacity (mean 4092, sd 64)
#define APITCH 68                       // fp32 agg row pitch (272 B, 16B aligned)
#define BPITCH 136                      // f16 Bt row pitch (272 B)

typedef _Float16 half8 __attribute__((ext_vector_type(8)));
typedef float f32x4 __attribute__((ext_vector_type(4)));

// ws layout (4B words), ~28 MB (same as R6):
//  [0, 2*NE)    rec (int2: .x = src | dstlocal<<20, .y = ew bits) — node-sorted
//  then sx[2NN] (float2: s1,x), p[NN], r[NN], nbase[NN], nend[NN], ghist/gbase/gcur[NB]

// -------- global histogram over dst buckets --------
__global__ __launch_bounds__(256) void k_hist(const int* __restrict__ dst,
                                              int* __restrict__ ghist) {
    __shared__ int sh[NB];
    for (int j = threadIdx.x; j < NB; j += 256) sh[j] = 0;
    __syncthreads();
    const long long b0 = (long long)blockIdx.x * CHUNK;
    #pragma unroll
    for (int k = 0; k < CHUNK / 256; ++k) {
        long long e = b0 + k * 256 + threadIdx.x;
        if (e < NE) atomicAdd(&sh[dst[e] >> 7], 1);
    }
    __syncthreads();
    for (int j = threadIdx.x; j < NB; j += 256) {
        int c = sh[j];
        if (c) atomicAdd(&ghist[j], c);
    }
}

// -------- exclusive scan of NB bucket counts (single WG) --------
__global__ void k_scan(const int* __restrict__ ghist, int* __restrict__ gbase,
                       int* __restrict__ gcur) {
    __shared__ int sh[1024];
    const int tid = threadIdx.x;
    int v = (tid < NB) ? ghist[tid] : 0;
    sh[tid] = v;
    __syncthreads();
    #pragma unroll
    for (int off = 1; off < 1024; off <<= 1) {
        int t = (tid >= off) ? sh[tid - off] : 0;
        __syncthreads();
        sh[tid] += t;
        __syncthreads();
    }
    if (tid < NB) {
        int b = sh[tid] - v;
        gbase[tid] = b;
        gcur[tid] = b;
    }
}

// -------- bucketed scatter: LDS-staged, one reservation atomic per (WG,bucket) --------
__global__ __launch_bounds__(256) void k_scatter(const int* __restrict__ src,
                                                 const int* __restrict__ dst,
                                                 const float* __restrict__ ew,
                                                 int* __restrict__ gcur,
                                                 int2* __restrict__ rec) {
    __shared__ int sh_px[CHUNK];
    __shared__ int sh_w[CHUNK];
    __shared__ unsigned short sh_b[CHUNK];
    __shared__ int sh_cnt[NB];
    __shared__ int sh_base[NB];
    for (int j = threadIdx.x; j < NB; j += 256) sh_cnt[j] = 0;
    __syncthreads();
    const long long b0 = (long long)blockIdx.x * CHUNK;
    #pragma unroll
    for (int k = 0; k < CHUNK / 256; ++k) {
        int idx = k * 256 + threadIdx.x;
        long long e = b0 + idx;
        if (e < NE) {
            int d = dst[e];
            int b = d >> 7;
            sh_px[idx] = src[e] | ((d & 127) << 20);   // src < 2^20
            sh_w[idx] = __float_as_int(ew[e]);
            sh_b[idx] = (unsigned short)b;
            atomicAdd(&sh_cnt[b], 1);
        }
    }
    __syncthreads();
    for (int j = threadIdx.x; j < NB; j += 256) {
        int c = sh_cnt[j];
        sh_base[j] = c ? atomicAdd(&gcur[j], c) : 0;
        sh_cnt[j] = 0;                                  // reuse as running offset
    }
    __syncthreads();
    #pragma unroll
    for (int k = 0; k < CHUNK / 256; ++k) {
        int idx = k * 256 + threadIdx.x;
        long long e = b0 + idx;
        if (e < NE) {
            int b = sh_b[idx];
            int off = atomicAdd(&sh_cnt[b], 1);
            rec[sh_base[b] + off] = make_int2(sh_px[idx], sh_w[idx]);
        }
    }
}

// -------- per-bucket counting sort by dstlocal + fused s1 + sx table + node CSR --------
__global__ __launch_bounds__(256) void k_sort(const int* __restrict__ gbase,
                                              const int* __restrict__ ghist,
                                              int2* __restrict__ rec,
                                              const float* __restrict__ x,
                                              float2* __restrict__ sx,
                                              int* __restrict__ nbase,
                                              int* __restrict__ nend) {
    __shared__ int2 lrec[CAP];          // 44 KB
    __shared__ int hist[NPB];
    __shared__ int excl[NPB];
    __shared__ int cur[NPB];
    __shared__ float loc[NPB];
    const int tid = threadIdx.x;
    if (tid < NPB) { hist[tid] = 0; loc[tid] = 0.f; }
    __syncthreads();
    const int b = blockIdx.x;
    const int beg = gbase[b];
    const int cnt = min(ghist[b], CAP);
    for (int t = tid; t < cnt; t += 256) {
        int2 rc = rec[beg + t];
        lrec[t] = rc;
        int dl = rc.x >> 20;
        atomicAdd(&hist[dl], 1);
        atomicAdd(&loc[dl], __int_as_float(rc.y) * x[rc.x & 0xFFFFF]);  // s1 fused
    }
    __syncthreads();
    if (tid < NPB) excl[tid] = hist[tid];
    __syncthreads();
    #pragma unroll
    for (int off = 1; off < NPB; off <<= 1) {
        int t = (tid < NPB && tid >= off) ? excl[tid - off] : 0;
        __syncthreads();
        if (tid < NPB) excl[tid] += t;
        __syncthreads();
    }
    if (tid < NPB) {
        int e0 = excl[tid] - hist[tid];         // exclusive
        cur[tid] = e0;
        int i = b * NPB + tid;
        if (i < NN) {
            nbase[i] = beg + e0;
            nend[i]  = beg + e0 + hist[tid];
            sx[i] = make_float2(loc[tid], x[i]);   // packed (s1, x)
        }
    }
    __syncthreads();
    for (int t = tid; t < cnt; t += 256) {
        int2 rc = lrec[t];
        int pos = atomicAdd(&cur[rc.x >> 20], 1);
        rec[beg + pos] = rc;                    // scatter within hot 32 KB window
    }
}

// -------- mega2: R6 register-acc edge loop (NO LDS atomics) + R9-verified MFMA --------
__global__ __launch_bounds__(256) void k_mega(
        const int* __restrict__ nbase, const int* __restrict__ nend,
        const int2* __restrict__ rec, const float2* __restrict__ sx,
        const float* __restrict__ W1_rel, const float* __restrict__ W1_root,
        const float* __restrict__ b1,
        const float* __restrict__ W2_rel, const float* __restrict__ b2,
        const float* __restrict__ W2_root,
        const float* __restrict__ W3_rel, const float* __restrict__ W3_root,
        float* __restrict__ p, float* __restrict__ r) {
    __shared__ float agg[NPB * APITCH];       // 34816 B
    __shared__ _Float16 Bt[HID * BPITCH];     // 17408 B, [n][k]: k<64 W2rel, k>=64 W2root
    __shared__ float2 sxl[NPB];               // 1024 B

    const int tid = threadIdx.x;
    const int f = tid & 63;
    const int wv = tid >> 6;
    const int b = blockIdx.x;
    const int gi0 = b * NPB;

    for (int idx = tid; idx < HID * HID; idx += 256) {
        int k = idx >> 6, n = idx & 63;
        Bt[n * BPITCH + k]       = (_Float16)W2_rel[idx];
        Bt[n * BPITCH + HID + k] = (_Float16)W2_root[idx];
    }
    if (tid < NPB) {
        int gi = gi0 + tid;
        sxl[tid] = (gi < NN) ? sx[gi] : make_float2(0.f, 0.f);
    }
    const float w1r = W1_rel[f], w1t = W1_root[f], b1f = b1[f];

    // ---- edge phase: wave owns 32 contiguous nodes; register acc; one ds_write/node ----
    for (int t = 0; t < 32; ++t) {
        const int n = wv * 32 + t;
        const int gi = gi0 + n;
        float a0 = 0.f, a1 = 0.f, a2 = 0.f, a3 = 0.f;
        if (gi < NN) {
            int e = nbase[gi];
            const int end = nend[gi];
            for (; e + 8 <= end; e += 8) {
                int2 q0 = rec[e],     q1 = rec[e + 1], q2 = rec[e + 2], q3 = rec[e + 3];
                int2 q4 = rec[e + 4], q5 = rec[e + 5], q6 = rec[e + 6], q7 = rec[e + 7];
                float2 v0 = sx[q0.x & 0xFFFFF];
                float2 v1 = sx[q1.x & 0xFFFFF];
                float2 v2 = sx[q2.x & 0xFFFFF];
                float2 v3 = sx[q3.x & 0xFFFFF];
                float2 v4 = sx[q4.x & 0xFFFFF];
                float2 v5 = sx[q5.x & 0xFFFFF];
                float2 v6 = sx[q6.x & 0xFFFFF];
                float2 v7 = sx[q7.x & 0xFFFFF];
                a0 = fmaf(__int_as_float(q0.y), fmaxf(0.f, fmaf(v0.x, w1r, fmaf(v0.y, w1t, b1f))), a0);
                a1 = fmaf(__int_as_float(q1.y), fmaxf(0.f, fmaf(v1.x, w1r, fmaf(v1.y, w1t, b1f))), a1);
                a2 = fmaf(__int_as_float(q2.y), fmaxf(0.f, fmaf(v2.x, w1r, fmaf(v2.y, w1t, b1f))), a2);
                a3 = fmaf(__int_as_float(q3.y), fmaxf(0.f, fmaf(v3.x, w1r, fmaf(v3.y, w1t, b1f))), a3);
                a0 = fmaf(__int_as_float(q4.y), fmaxf(0.f, fmaf(v4.x, w1r, fmaf(v4.y, w1t, b1f))), a0);
                a1 = fmaf(__int_as_float(q5.y), fmaxf(0.f, fmaf(v5.x, w1r, fmaf(v5.y, w1t, b1f))), a1);
                a2 = fmaf(__int_as_float(q6.y), fmaxf(0.f, fmaf(v6.x, w1r, fmaf(v6.y, w1t, b1f))), a2);
                a3 = fmaf(__int_as_float(q7.y), fmaxf(0.f, fmaf(v7.x, w1r, fmaf(v7.y, w1t, b1f))), a3);
            }
            for (; e < end; ++e) {
                int2 q0 = rec[e];
                float2 sv = sx[q0.x & 0xFFFFF];
                a0 = fmaf(__int_as_float(q0.y),
                          fmaxf(0.f, fmaf(sv.x, w1r, fmaf(sv.y, w1t, b1f))), a0);
            }
        }
        agg[n * APITCH + f] = (a0 + a1) + (a2 + a3);   // plain ds_write, 2-way banks
    }
    __syncthreads();

    // ---- MFMA: O[128,64] = [AGG | H1] @ [W2rel ; W2root]  (layouts verified in R9) ----
    const int lane = tid & 63;
    const int m16 = lane & 15;
    const int quad = lane >> 4;
    f32x4 acc[2][4];
    #pragma unroll
    for (int a_ = 0; a_ < 2; ++a_)
        #pragma unroll
        for (int c_ = 0; c_ < 4; ++c_)
            acc[a_][c_] = (f32x4){0.f, 0.f, 0.f, 0.f};

    const float2 sm0 = sxl[(2 * wv + 0) * 16 + m16];
    const float2 sm1 = sxl[(2 * wv + 1) * 16 + m16];

    #pragma unroll
    for (int kt = 0; kt < 4; ++kt) {
        const int kk = kt * 32;
        half8 a0, a1;
        if (kt < 2) {
            const float* pa0 = &agg[((2 * wv + 0) * 16 + m16) * APITCH + kk + quad * 8];
            const float* pa1 = &agg[((2 * wv + 1) * 16 + m16) * APITCH + kk + quad * 8];
            #pragma unroll
            for (int j = 0; j < 8; ++j) {
                a0[j] = (_Float16)pa0[j];
                a1[j] = (_Float16)pa1[j];
            }
        } else {
            const int fk0 = (kt - 2) * 32 + quad * 8;
            #pragma unroll
            for (int j = 0; j < 8; ++j) {
                const float wr = W1_rel[fk0 + j], wt = W1_root[fk0 + j], bb = b1[fk0 + j];
                a0[j] = (_Float16)fmaxf(0.f, fmaf(sm0.x, wr, fmaf(sm0.y, wt, bb)));
                a1[j] = (_Float16)fmaxf(0.f, fmaf(sm1.x, wr, fmaf(sm1.y, wt, bb)));
            }
        }
        #pragma unroll
        for (int ct = 0; ct < 4; ++ct) {
            const half8 bfrag = *(const half8*)&Bt[(ct * 16 + m16) * BPITCH + kk + quad * 8];
            acc[0][ct] = __builtin_amdgcn_mfma_f32_16x16x32_f16(a0, bfrag, acc[0][ct], 0, 0, 0);
            acc[1][ct] = __builtin_amdgcn_mfma_f32_16x16x32_f16(a1, bfrag, acc[1][ct], 0, 0, 0);
        }
    }

    float b2c[4], w3rc[4], w3tc[4];
    #pragma unroll
    for (int ct = 0; ct < 4; ++ct) {
        const int col = ct * 16 + m16;
        b2c[ct] = b2[col]; w3rc[ct] = W3_rel[col]; w3tc[ct] = W3_root[col];
    }
    #pragma unroll
    for (int rt = 0; rt < 2; ++rt) {
        float pv[4] = {0.f, 0.f, 0.f, 0.f}, rv[4] = {0.f, 0.f, 0.f, 0.f};
        #pragma unroll
        for (int ct = 0; ct < 4; ++ct) {
            #pragma unroll
            for (int reg = 0; reg < 4; ++reg) {
                const float h2 = fmaxf(0.f, acc[rt][ct][reg] + b2c[ct]);
                pv[reg] = fmaf(h2, w3rc[ct], pv[reg]);
                rv[reg] = fmaf(h2, w3tc[ct], rv[reg]);
            }
        }
        #pragma unroll
        for (int reg = 0; reg < 4; ++reg) {
            #pragma unroll
            for (int msk = 1; msk < 16; msk <<= 1) {
                pv[reg] += __shfl_xor(pv[reg], msk, 64);
                rv[reg] += __shfl_xor(rv[reg], msk, 64);
            }
        }
        if (m16 == 0) {
            #pragma unroll
            for (int reg = 0; reg < 4; ++reg) {
                const int gi = gi0 + (2 * wv + rt) * 16 + quad * 4 + reg;
                if (gi < NN) { p[gi] = pv[reg]; r[gi] = rv[reg]; }
            }
        }
    }
}

// -------- bucketed output: out = seg_sum(w * p[src]) + r + b3 --------
__global__ __launch_bounds__(256) void k_out(const int* __restrict__ gbase,
                                             const int* __restrict__ ghist,
                                             const int2* __restrict__ rec,
                                             const float* __restrict__ pp,
                                             const float* __restrict__ rr,
                                             const float* __restrict__ b3,
                                             float* __restrict__ out) {
    __shared__ float loc[NPB];
    if (threadIdx.x < NPB) loc[threadIdx.x] = 0.f;
    __syncthreads();
    const int b = blockIdx.x;
    const int beg = gbase[b], cnt = ghist[b];
    for (int t = threadIdx.x; t < cnt; t += 256) {
        int2 rc = rec[beg + t];
        atomicAdd(&loc[rc.x >> 20], __int_as_float(rc.y) * pp[rc.x & 0xFFFFF]);
    }
    __syncthreads();
    int i = b * NPB + threadIdx.x;
    if (threadIdx.x < NPB && i < NN) out[i] = loc[threadIdx.x] + rr[i] + b3[0];
}

extern "C" void kernel_launch(void* const* d_in, const int* in_sizes, int n_in,
                              void* d_out, int out_size, void* d_ws, size_t ws_size,
                              hipStream_t stream) {
    const float* x       = (const float*)d_in[0];
    const int*   ei      = (const int*)  d_in[1];
    const float* ew      = (const float*)d_in[2];
    const float* W1_rel  = (const float*)d_in[3];
    const float* b1      = (const float*)d_in[4];
    const float* W1_root = (const float*)d_in[5];
    const float* W2_rel  = (const float*)d_in[6];
    const float* b2      = (const float*)d_in[7];
    const float* W2_root = (const float*)d_in[8];
    const float* W3_rel  = (const float*)d_in[9];
    const float* b3      = (const float*)d_in[10];
    const float* W3_root = (const float*)d_in[11];

    const int* src = ei;
    const int* dst = ei + NE;

    int2*   rec   = (int2*)d_ws;
    float2* sx    = (float2*)((int*)d_ws + 2 * (size_t)NE);
    float*  p     = (float*)(sx + NN);
    float*  r     = p + NN;
    int*    nbase = (int*)(r + NN);
    int*    nend  = nbase + NN;
    int*    ghist = nend + NN;
    int*    gbase = ghist + NB;
    int*    gcur  = gbase + NB;

    hipMemsetAsync(ghist, 0, NB * sizeof(int), stream);

    k_hist<<<NCH, 256, 0, stream>>>(dst, ghist);
    k_scan<<<1, 1024, 0, stream>>>(ghist, gbase, gcur);
    k_scatter<<<NCH, 256, 0, stream>>>(src, dst, ew, gcur, rec);
    k_sort<<<NB, 256, 0, stream>>>(gbase, ghist, rec, x, sx, nbase, nend);
    k_mega<<<NB, 256, 0, stream>>>(nbase, nend, rec, sx,
                                   W1_rel, W1_root, b1,
                                   W2_rel, b2, W2_root,
                                   W3_rel, W3_root, p, r);
    k_out<<<NB, 256, 0, stream>>>(gbase, ghist, rec, p, r, b3, (float*)d_out);
}

// Round 11
// 440.557 us; speedup vs baseline: 3.5560x; 1.1227x over previous
//
#include <hip/hip_runtime.h>

#define NN 100000
#define NE 3200000
#define HID 64
#define NPB 128                         // nodes per bucket (dstlocal = dst & 127)
#define NB  ((NN + NPB - 1) / NPB)      // 782 buckets
#define CHUNK 4096                      // edges per hist/scatter workgroup
#define NCH ((NE + CHUNK - 1) / CHUNK)  // 782 chunks
#define CAP 5632                        // per-bucket record capacity (mean 4092, sd 64)
#define AP 72                           // f16 agg row pitch in halfs (144 B, 16B-aligned)
#define BPITCH 136                      // f16 Bt row pitch in halfs (272 B)

typedef _Float16 half8 __attribute__((ext_vector_type(8)));
typedef float f32x4 __attribute__((ext_vector_type(4)));

// ws layout (4B words), ~28 MB (same as R6/R10):
//  [0, 2*NE)    rec (int2: .x = src | dstlocal<<20, .y = ew bits) — node-sorted
//  then sx[2NN] (float2: s1,x), p[NN], r[NN], nbase[NN], nend[NN], ghist/gbase/gcur[NB]

// -------- global histogram over dst buckets --------
__global__ __launch_bounds__(256) void k_hist(const int* __restrict__ dst,
                                              int* __restrict__ ghist) {
    __shared__ int sh[NB];
    for (int j = threadIdx.x; j < NB; j += 256) sh[j] = 0;
    __syncthreads();
    const long long b0 = (long long)blockIdx.x * CHUNK;
    #pragma unroll
    for (int k = 0; k < CHUNK / 256; ++k) {
        long long e = b0 + k * 256 + threadIdx.x;
        if (e < NE) atomicAdd(&sh[dst[e] >> 7], 1);
    }
    __syncthreads();
    for (int j = threadIdx.x; j < NB; j += 256) {
        int c = sh[j];
        if (c) atomicAdd(&ghist[j], c);
    }
}

// -------- exclusive scan of NB bucket counts (single WG) --------
__global__ void k_scan(const int* __restrict__ ghist, int* __restrict__ gbase,
                       int* __restrict__ gcur) {
    __shared__ int sh[1024];
    const int tid = threadIdx.x;
    int v = (tid < NB) ? ghist[tid] : 0;
    sh[tid] = v;
    __syncthreads();
    #pragma unroll
    for (int off = 1; off < 1024; off <<= 1) {
        int t = (tid >= off) ? sh[tid - off] : 0;
        __syncthreads();
        sh[tid] += t;
        __syncthreads();
    }
    if (tid < NB) {
        int b = sh[tid] - v;
        gbase[tid] = b;
        gcur[tid] = b;
    }
}

// -------- bucketed scatter: LDS-staged, one reservation atomic per (WG,bucket) --------
__global__ __launch_bounds__(256) void k_scatter(const int* __restrict__ src,
                                                 const int* __restrict__ dst,
                                                 const float* __restrict__ ew,
                                                 int* __restrict__ gcur,
                                                 int2* __restrict__ rec) {
    __shared__ int sh_px[CHUNK];
    __shared__ int sh_w[CHUNK];
    __shared__ unsigned short sh_b[CHUNK];
    __shared__ int sh_cnt[NB];
    __shared__ int sh_base[NB];
    for (int j = threadIdx.x; j < NB; j += 256) sh_cnt[j] = 0;
    __syncthreads();
    const long long b0 = (long long)blockIdx.x * CHUNK;
    #pragma unroll
    for (int k = 0; k < CHUNK / 256; ++k) {
        int idx = k * 256 + threadIdx.x;
        long long e = b0 + idx;
        if (e < NE) {
            int d = dst[e];
            int b = d >> 7;
            sh_px[idx] = src[e] | ((d & 127) << 20);   // src < 2^20
            sh_w[idx] = __float_as_int(ew[e]);
            sh_b[idx] = (unsigned short)b;
            atomicAdd(&sh_cnt[b], 1);
        }
    }
    __syncthreads();
    for (int j = threadIdx.x; j < NB; j += 256) {
        int c = sh_cnt[j];
        sh_base[j] = c ? atomicAdd(&gcur[j], c) : 0;
        sh_cnt[j] = 0;                                  // reuse as running offset
    }
    __syncthreads();
    #pragma unroll
    for (int k = 0; k < CHUNK / 256; ++k) {
        int idx = k * 256 + threadIdx.x;
        long long e = b0 + idx;
        if (e < NE) {
            int b = sh_b[idx];
            int off = atomicAdd(&sh_cnt[b], 1);
            rec[sh_base[b] + off] = make_int2(sh_px[idx], sh_w[idx]);
        }
    }
}

// -------- per-bucket counting sort by dstlocal + fused s1 + sx table + node CSR --------
__global__ __launch_bounds__(256) void k_sort(const int* __restrict__ gbase,
                                              const int* __restrict__ ghist,
                                              int2* __restrict__ rec,
                                              const float* __restrict__ x,
                                              float2* __restrict__ sx,
                                              int* __restrict__ nbase,
                                              int* __restrict__ nend) {
    __shared__ int2 lrec[CAP];          // 44 KB
    __shared__ int hist[NPB];
    __shared__ int excl[NPB];
    __shared__ int cur[NPB];
    __shared__ float loc[NPB];
    const int tid = threadIdx.x;
    if (tid < NPB) { hist[tid] = 0; loc[tid] = 0.f; }
    __syncthreads();
    const int b = blockIdx.x;
    const int beg = gbase[b];
    const int cnt = min(ghist[b], CAP);
    for (int t = tid; t < cnt; t += 256) {
        int2 rc = rec[beg + t];
        lrec[t] = rc;
        int dl = rc.x >> 20;
        atomicAdd(&hist[dl], 1);
        atomicAdd(&loc[dl], __int_as_float(rc.y) * x[rc.x & 0xFFFFF]);  // s1 fused
    }
    __syncthreads();
    if (tid < NPB) excl[tid] = hist[tid];
    __syncthreads();
    #pragma unroll
    for (int off = 1; off < NPB; off <<= 1) {
        int t = (tid < NPB && tid >= off) ? excl[tid - off] : 0;
        __syncthreads();
        if (tid < NPB) excl[tid] += t;
        __syncthreads();
    }
    if (tid < NPB) {
        int e0 = excl[tid] - hist[tid];         // exclusive
        cur[tid] = e0;
        int i = b * NPB + tid;
        if (i < NN) {
            nbase[i] = beg + e0;
            nend[i]  = beg + e0 + hist[tid];
            sx[i] = make_float2(loc[tid], x[i]);   // packed (s1, x)
        }
    }
    __syncthreads();
    for (int t = tid; t < cnt; t += 256) {
        int2 rc = lrec[t];
        int pos = atomicAdd(&cur[rc.x >> 20], 1);
        rec[beg + pos] = rc;                    // scatter within hot 32 KB window
    }
}

// -------- mega: streaming node-aligned edge phase (f16 agg, no atomics, no tails)
//          + verified MFMA epilogue --------
__global__ __launch_bounds__(256) void k_mega(
        const int* __restrict__ nbase, const int* __restrict__ nend,
        const int2* __restrict__ rec, const float2* __restrict__ sx,
        const float* __restrict__ W1_rel, const float* __restrict__ W1_root,
        const float* __restrict__ b1,
        const float* __restrict__ W2_rel, const float* __restrict__ b2,
        const float* __restrict__ W2_root,
        const float* __restrict__ W3_rel, const float* __restrict__ W3_root,
        float* __restrict__ p, float* __restrict__ r) {
    __shared__ _Float16 aggh[NPB * AP];       // 18432 B (f16 aggregate)
    __shared__ _Float16 Bt[HID * BPITCH];     // 17408 B, [n][k]: k<64 W2rel, k>=64 W2root
    __shared__ float2 sxl[NPB];               // 1024 B   -> total ~36.9 KB, 4 blocks/CU

    const int tid = threadIdx.x;
    const int f = tid & 63;
    const int wv = tid >> 6;
    const int b = blockIdx.x;
    const int gi0 = b * NPB;

    // init: zero agg, stage Bt + sxl
    for (int j = tid; j < NPB * AP / 2; j += 256) ((int*)aggh)[j] = 0;
    for (int idx = tid; idx < HID * HID; idx += 256) {
        int k = idx >> 6, n = idx & 63;
        Bt[n * BPITCH + k]       = (_Float16)W2_rel[idx];
        Bt[n * BPITCH + HID + k] = (_Float16)W2_root[idx];
    }
    if (tid < NPB) {
        int gi = gi0 + tid;
        sxl[tid] = (gi < NN) ? sx[gi] : make_float2(0.f, 0.f);
    }
    const float w1r = W1_rel[f], w1t = W1_root[f], b1f = b1[f];
    __syncthreads();

    // ---- streaming edge phase: wave owns nodes [first, first+31] = one contiguous
    //      record range (k_sort). Flush acc on dl change: plain f16 ds_write. ----
    {
        const int first = gi0 + wv * 32;
        int e = 0, eend = 0;
        if (first < NN) {
            e = nbase[first];
            eend = nend[min(first + 31, NN - 1)];
        }
        int curn = -1;
        float a0 = 0.f, a1 = 0.f, a2 = 0.f, a3 = 0.f;

#define PROC(QQ, VV, AA)                                                          \
        {                                                                         \
            const int dl_ = (QQ).x >> 20;                                         \
            if (dl_ != curn) {                                                    \
                if (curn >= 0) aggh[curn * AP + f] = (_Float16)((a0 + a1) + (a2 + a3)); \
                curn = dl_; a0 = a1 = a2 = a3 = 0.f;                              \
            }                                                                     \
            const float h_ = fmaxf(0.f, fmaf((VV).x, w1r, fmaf((VV).y, w1t, b1f))); \
            AA = fmaf(__int_as_float((QQ).y), h_, AA);                            \
        }

        int2 q0, q1, q2, q3, q4, q5, q6, q7;
        bool have = (e + 8 <= eend);
        if (have) {
            q0 = rec[e];     q1 = rec[e + 1]; q2 = rec[e + 2]; q3 = rec[e + 3];
            q4 = rec[e + 4]; q5 = rec[e + 5]; q6 = rec[e + 6]; q7 = rec[e + 7];
        }
        while (have) {
            float2 v0 = sx[q0.x & 0xFFFFF];
            float2 v1 = sx[q1.x & 0xFFFFF];
            float2 v2 = sx[q2.x & 0xFFFFF];
            float2 v3 = sx[q3.x & 0xFFFFF];
            float2 v4 = sx[q4.x & 0xFFFFF];
            float2 v5 = sx[q5.x & 0xFFFFF];
            float2 v6 = sx[q6.x & 0xFFFFF];
            float2 v7 = sx[q7.x & 0xFFFFF];
            int2 n0, n1, n2, n3, n4, n5, n6, n7;
            const bool nxt = (e + 16 <= eend);
            if (nxt) {  // prefetch next batch (overlaps compute)
                n0 = rec[e + 8];  n1 = rec[e + 9];  n2 = rec[e + 10]; n3 = rec[e + 11];
                n4 = rec[e + 12]; n5 = rec[e + 13]; n6 = rec[e + 14]; n7 = rec[e + 15];
            }
            PROC(q0, v0, a0) PROC(q1, v1, a1) PROC(q2, v2, a2) PROC(q3, v3, a3)
            PROC(q4, v4, a0) PROC(q5, v5, a1) PROC(q6, v6, a2) PROC(q7, v7, a3)
            e += 8;
            have = nxt;
            if (nxt) {
                q0 = n0; q1 = n1; q2 = n2; q3 = n3;
                q4 = n4; q5 = n5; q6 = n6; q7 = n7;
            }
        }
        for (; e < eend; ++e) {
            int2 qq = rec[e];
            float2 vv = sx[qq.x & 0xFFFFF];
            PROC(qq, vv, a0)
        }
        if (curn >= 0) aggh[curn * AP + f] = (_Float16)((a0 + a1) + (a2 + a3));
#undef PROC
    }
    __syncthreads();

    // ---- MFMA: O[128,64] = [AGG | H1] @ [W2rel ; W2root]  (layouts verified R9/R10) ----
    const int lane = tid & 63;
    const int m16 = lane & 15;
    const int quad = lane >> 4;
    f32x4 acc[2][4];
    #pragma unroll
    for (int a_ = 0; a_ < 2; ++a_)
        #pragma unroll
        for (int c_ = 0; c_ < 4; ++c_)
            acc[a_][c_] = (f32x4){0.f, 0.f, 0.f, 0.f};

    const float2 sm0 = sxl[(2 * wv + 0) * 16 + m16];
    const float2 sm1 = sxl[(2 * wv + 1) * 16 + m16];

    #pragma unroll
    for (int kt = 0; kt < 4; ++kt) {
        const int kk = kt * 32;
        half8 a0, a1;
        if (kt < 2) {
            a0 = *(const half8*)&aggh[((2 * wv + 0) * 16 + m16) * AP + kk + quad * 8];
            a1 = *(const half8*)&aggh[((2 * wv + 1) * 16 + m16) * AP + kk + quad * 8];
        } else {
            const int fk0 = (kt - 2) * 32 + quad * 8;
            #pragma unroll
            for (int j = 0; j < 8; ++j) {
                const float wr = W1_rel[fk0 + j], wt = W1_root[fk0 + j], bb = b1[fk0 + j];
                a0[j] = (_Float16)fmaxf(0.f, fmaf(sm0.x, wr, fmaf(sm0.y, wt, bb)));
                a1[j] = (_Float16)fmaxf(0.f, fmaf(sm1.x, wr, fmaf(sm1.y, wt, bb)));
            }
        }
        #pragma unroll
        for (int ct = 0; ct < 4; ++ct) {
            const half8 bfrag = *(const half8*)&Bt[(ct * 16 + m16) * BPITCH + kk + quad * 8];
            acc[0][ct] = __builtin_amdgcn_mfma_f32_16x16x32_f16(a0, bfrag, acc[0][ct], 0, 0, 0);
            acc[1][ct] = __builtin_amdgcn_mfma_f32_16x16x32_f16(a1, bfrag, acc[1][ct], 0, 0, 0);
        }
    }

    float b2c[4], w3rc[4], w3tc[4];
    #pragma unroll
    for (int ct = 0; ct < 4; ++ct) {
        const int col = ct * 16 + m16;
        b2c[ct] = b2[col]; w3rc[ct] = W3_rel[col]; w3tc[ct] = W3_root[col];
    }
    #pragma unroll
    for (int rt = 0; rt < 2; ++rt) {
        float pv[4] = {0.f, 0.f, 0.f, 0.f}, rv[4] = {0.f, 0.f, 0.f, 0.f};
        #pragma unroll
        for (int ct = 0; ct < 4; ++ct) {
            #pragma unroll
            for (int reg = 0; reg < 4; ++reg) {
                const float h2 = fmaxf(0.f, acc[rt][ct][reg] + b2c[ct]);
                pv[reg] = fmaf(h2, w3rc[ct], pv[reg]);
                rv[reg] = fmaf(h2, w3tc[ct], rv[reg]);
            }
        }
        #pragma unroll
        for (int reg = 0; reg < 4; ++reg) {
            #pragma unroll
            for (int msk = 1; msk < 16; msk <<= 1) {
                pv[reg] += __shfl_xor(pv[reg], msk, 64);
                rv[reg] += __shfl_xor(rv[reg], msk, 64);
            }
        }
        if (m16 == 0) {
            #pragma unroll
            for (int reg = 0; reg < 4; ++reg) {
                const int gi = gi0 + (2 * wv + rt) * 16 + quad * 4 + reg;
                if (gi < NN) { p[gi] = pv[reg]; r[gi] = rv[reg]; }
            }
        }
    }
}

// -------- bucketed output: out = seg_sum(w * p[src]) + r + b3 --------
__global__ __launch_bounds__(256) void k_out(const int* __restrict__ gbase,
                                             const int* __restrict__ ghist,
                                             const int2* __restrict__ rec,
                                             const float* __restrict__ pp,
                                             const float* __restrict__ rr,
                                             const float* __restrict__ b3,
                                             float* __restrict__ out) {
    __shared__ float loc[NPB];
    if (threadIdx.x < NPB) loc[threadIdx.x] = 0.f;
    __syncthreads();
    const int b = blockIdx.x;
    const int beg = gbase[b], cnt = ghist[b];
    for (int t = threadIdx.x; t < cnt; t += 256) {
        int2 rc = rec[beg + t];
        atomicAdd(&loc[rc.x >> 20], __int_as_float(rc.y) * pp[rc.x & 0xFFFFF]);
    }
    __syncthreads();
    int i = b * NPB + threadIdx.x;
    if (threadIdx.x < NPB && i < NN) out[i] = loc[threadIdx.x] + rr[i] + b3[0];
}

extern "C" void kernel_launch(void* const* d_in, const int* in_sizes, int n_in,
                              void* d_out, int out_size, void* d_ws, size_t ws_size,
                              hipStream_t stream) {
    const float* x       = (const float*)d_in[0];
    const int*   ei      = (const int*)  d_in[1];
    const float* ew      = (const float*)d_in[2];
    const float* W1_rel  = (const float*)d_in[3];
    const float* b1      = (const float*)d_in[4];
    const float* W1_root = (const float*)d_in[5];
    const float* W2_rel  = (const float*)d_in[6];
    const float* b2      = (const float*)d_in[7];
    const float* W2_root = (const float*)d_in[8];
    const float* W3_rel  = (const float*)d_in[9];
    const float* b3      = (const float*)d_in[10];
    const float* W3_root = (const float*)d_in[11];

    const int* src = ei;
    const int* dst = ei + NE;

    int2*   rec   = (int2*)d_ws;
    float2* sx    = (float2*)((int*)d_ws + 2 * (size_t)NE);
    float*  p     = (float*)(sx + NN);
    float*  r     = p + NN;
    int*    nbase = (int*)(r + NN);
    int*    nend  = nbase + NN;
    int*    ghist = nend + NN;
    int*    gbase = ghist + NB;
    int*    gcur  = gbase + NB;

    hipMemsetAsync(ghist, 0, NB * sizeof(int), stream);

    k_hist<<<NCH, 256, 0, stream>>>(dst, ghist);
    k_scan<<<1, 1024, 0, stream>>>(ghist, gbase, gcur);
    k_scatter<<<NCH, 256, 0, stream>>>(src, dst, ew, gcur, rec);
    k_sort<<<NB, 256, 0, stream>>>(gbase, ghist, rec, x, sx, nbase, nend);
    k_mega<<<NB, 256, 0, stream>>>(nbase, nend, rec, sx,
                                   W1_rel, W1_root, b1,
                                   W2_rel, b2, W2_root,
                                   W3_rel, W3_root, p, r);
    k_out<<<NB, 256, 0, stream>>>(gbase, ghist, rec, p, r, b3, (float*)d_out);
}

// Round 12
// 422.961 us; speedup vs baseline: 3.7040x; 1.0416x over previous
//
#include <hip/hip_runtime.h>

#define NN 100000
#define NE 3200000
#define HID 64
#define NPB 128                         // nodes per bucket (dstlocal = dst & 127)
#define NB  ((NN + NPB - 1) / NPB)      // 782 buckets
#define NPB2 64                         // nodes per k_mega block (half bucket)
#define NB2 (NB * 2)                    // 1564 mega blocks
#define CHUNK 4096                      // edges per hist/scatter workgroup
#define NCH ((NE + CHUNK - 1) / CHUNK)  // 782 chunks
#define CAP 5632                        // per-bucket record capacity (mean 4092, sd 64)
#define AP 72                           // f16 agg row pitch in halfs (144 B, 16B-aligned)
#define BPITCH 136                      // f16 Bt row pitch in halfs (272 B)

typedef _Float16 half8 __attribute__((ext_vector_type(8)));
typedef float f32x4 __attribute__((ext_vector_type(4)));

// ws layout (4B words), ~28 MB (same as R6/R10/R11):
//  [0, 2*NE)    rec (int2: .x = src | dstlocal<<20, .y = ew bits) — node-sorted
//  then sx[2NN] (float2: s1,x), p[NN], r[NN], nbase[NN], nend[NN], ghist/gbase/gcur[NB]

// -------- global histogram over dst buckets --------
__global__ __launch_bounds__(256) void k_hist(const int* __restrict__ dst,
                                              int* __restrict__ ghist) {
    __shared__ int sh[NB];
    for (int j = threadIdx.x; j < NB; j += 256) sh[j] = 0;
    __syncthreads();
    const long long b0 = (long long)blockIdx.x * CHUNK;
    #pragma unroll
    for (int k = 0; k < CHUNK / 256; ++k) {
        long long e = b0 + k * 256 + threadIdx.x;
        if (e < NE) atomicAdd(&sh[dst[e] >> 7], 1);
    }
    __syncthreads();
    for (int j = threadIdx.x; j < NB; j += 256) {
        int c = sh[j];
        if (c) atomicAdd(&ghist[j], c);
    }
}

// -------- exclusive scan of NB bucket counts (single WG) --------
__global__ void k_scan(const int* __restrict__ ghist, int* __restrict__ gbase,
                       int* __restrict__ gcur) {
    __shared__ int sh[1024];
    const int tid = threadIdx.x;
    int v = (tid < NB) ? ghist[tid] : 0;
    sh[tid] = v;
    __syncthreads();
    #pragma unroll
    for (int off = 1; off < 1024; off <<= 1) {
        int t = (tid >= off) ? sh[tid - off] : 0;
        __syncthreads();
        sh[tid] += t;
        __syncthreads();
    }
    if (tid < NB) {
        int b = sh[tid] - v;
        gbase[tid] = b;
        gcur[tid] = b;
    }
}

// -------- bucketed scatter: LDS-staged, one reservation atomic per (WG,bucket) --------
__global__ __launch_bounds__(256) void k_scatter(const int* __restrict__ src,
                                                 const int* __restrict__ dst,
                                                 const float* __restrict__ ew,
                                                 int* __restrict__ gcur,
                                                 int2* __restrict__ rec) {
    __shared__ int sh_px[CHUNK];
    __shared__ int sh_w[CHUNK];
    __shared__ unsigned short sh_b[CHUNK];
    __shared__ int sh_cnt[NB];
    __shared__ int sh_base[NB];
    for (int j = threadIdx.x; j < NB; j += 256) sh_cnt[j] = 0;
    __syncthreads();
    const long long b0 = (long long)blockIdx.x * CHUNK;
    #pragma unroll
    for (int k = 0; k < CHUNK / 256; ++k) {
        int idx = k * 256 + threadIdx.x;
        long long e = b0 + idx;
        if (e < NE) {
            int d = dst[e];
            int b = d >> 7;
            sh_px[idx] = src[e] | ((d & 127) << 20);   // src < 2^20
            sh_w[idx] = __float_as_int(ew[e]);
            sh_b[idx] = (unsigned short)b;
            atomicAdd(&sh_cnt[b], 1);
        }
    }
    __syncthreads();
    for (int j = threadIdx.x; j < NB; j += 256) {
        int c = sh_cnt[j];
        sh_base[j] = c ? atomicAdd(&gcur[j], c) : 0;
        sh_cnt[j] = 0;                                  // reuse as running offset
    }
    __syncthreads();
    #pragma unroll
    for (int k = 0; k < CHUNK / 256; ++k) {
        int idx = k * 256 + threadIdx.x;
        long long e = b0 + idx;
        if (e < NE) {
            int b = sh_b[idx];
            int off = atomicAdd(&sh_cnt[b], 1);
            rec[sh_base[b] + off] = make_int2(sh_px[idx], sh_w[idx]);
        }
    }
}

// -------- per-bucket counting sort by dstlocal + fused s1 + sx table + node CSR --------
__global__ __launch_bounds__(256) void k_sort(const int* __restrict__ gbase,
                                              const int* __restrict__ ghist,
                                              int2* __restrict__ rec,
                                              const float* __restrict__ x,
                                              float2* __restrict__ sx,
                                              int* __restrict__ nbase,
                                              int* __restrict__ nend) {
    __shared__ int2 lrec[CAP];          // 44 KB
    __shared__ int hist[NPB];
    __shared__ int excl[NPB];
    __shared__ int cur[NPB];
    __shared__ float loc[NPB];
    const int tid = threadIdx.x;
    if (tid < NPB) { hist[tid] = 0; loc[tid] = 0.f; }
    __syncthreads();
    const int b = blockIdx.x;
    const int beg = gbase[b];
    const int cnt = min(ghist[b], CAP);
    for (int t = tid; t < cnt; t += 256) {
        int2 rc = rec[beg + t];
        lrec[t] = rc;
        int dl = rc.x >> 20;
        atomicAdd(&hist[dl], 1);
        atomicAdd(&loc[dl], __int_as_float(rc.y) * x[rc.x & 0xFFFFF]);  // s1 fused
    }
    __syncthreads();
    if (tid < NPB) excl[tid] = hist[tid];
    __syncthreads();
    #pragma unroll
    for (int off = 1; off < NPB; off <<= 1) {
        int t = (tid < NPB && tid >= off) ? excl[tid - off] : 0;
        __syncthreads();
        if (tid < NPB) excl[tid] += t;
        __syncthreads();
    }
    if (tid < NPB) {
        int e0 = excl[tid] - hist[tid];         // exclusive
        cur[tid] = e0;
        int i = b * NPB + tid;
        if (i < NN) {
            nbase[i] = beg + e0;
            nend[i]  = beg + e0 + hist[tid];
            sx[i] = make_float2(loc[tid], x[i]);   // packed (s1, x)
        }
    }
    __syncthreads();
    for (int t = tid; t < cnt; t += 256) {
        int2 rc = lrec[t];
        int pos = atomicAdd(&cur[rc.x >> 20], 1);
        rec[beg + pos] = rc;                    // scatter within hot 32 KB window
    }
}

// -------- mega: half-bucket blocks (64 nodes) for 2x grid / 5 blocks-per-CU LDS --------
__global__ __launch_bounds__(256) void k_mega(
        const int* __restrict__ nbase, const int* __restrict__ nend,
        const int2* __restrict__ rec, const float2* __restrict__ sx,
        const float* __restrict__ W1_rel, const float* __restrict__ W1_root,
        const float* __restrict__ b1,
        const float* __restrict__ W2_rel, const float* __restrict__ b2,
        const float* __restrict__ W2_root,
        const float* __restrict__ W3_rel, const float* __restrict__ W3_root,
        float* __restrict__ p, float* __restrict__ r) {
    __shared__ _Float16 aggh[NPB2 * AP];      // 9216 B (f16 aggregate, 64 rows)
    __shared__ _Float16 Bt[HID * BPITCH];     // 17408 B, [n][k]: k<64 W2rel, k>=64 W2root
    __shared__ float2 sxl[NPB2];              // 512 B   -> total ~27.1 KB, 5 blocks/CU

    const int tid = threadIdx.x;
    const int f = tid & 63;
    const int wv = tid >> 6;
    const int gi0 = blockIdx.x * NPB2;        // 64-node window (half bucket)

    // init: zero agg, stage Bt + sxl
    for (int j = tid; j < NPB2 * AP / 2; j += 256) ((int*)aggh)[j] = 0;
    for (int idx = tid; idx < HID * HID; idx += 256) {
        int k = idx >> 6, n = idx & 63;
        Bt[n * BPITCH + k]       = (_Float16)W2_rel[idx];
        Bt[n * BPITCH + HID + k] = (_Float16)W2_root[idx];
    }
    if (tid < NPB2) {
        int gi = gi0 + tid;
        sxl[tid] = (gi < NN) ? sx[gi] : make_float2(0.f, 0.f);
    }
    const float w1r = W1_rel[f], w1t = W1_root[f], b1f = b1[f];
    __syncthreads();

    // ---- streaming edge phase: wave owns 16 contiguous nodes = one contiguous
    //      record range (k_sort). Flush acc on dl change: plain f16 ds_write. ----
    {
        const int first = gi0 + wv * 16;
        int e = 0, eend = 0;
        if (first < NN) {
            e = nbase[first];
            eend = nend[min(first + 15, NN - 1)];
        }
        int curn = -1;
        float a0 = 0.f, a1 = 0.f, a2 = 0.f, a3 = 0.f;

#define PROC(QQ, VV, AA)                                                          \
        {                                                                         \
            const int dl_ = (QQ).x >> 20;                                         \
            if (dl_ != curn) {                                                    \
                if (curn >= 0) aggh[(curn & 63) * AP + f] = (_Float16)((a0 + a1) + (a2 + a3)); \
                curn = dl_; a0 = a1 = a2 = a3 = 0.f;                              \
            }                                                                     \
            const float h_ = fmaxf(0.f, fmaf((VV).x, w1r, fmaf((VV).y, w1t, b1f))); \
            AA = fmaf(__int_as_float((QQ).y), h_, AA);                            \
        }

        int2 q0, q1, q2, q3, q4, q5, q6, q7;
        bool have = (e + 8 <= eend);
        if (have) {
            q0 = rec[e];     q1 = rec[e + 1]; q2 = rec[e + 2]; q3 = rec[e + 3];
            q4 = rec[e + 4]; q5 = rec[e + 5]; q6 = rec[e + 6]; q7 = rec[e + 7];
        }
        while (have) {
            float2 v0 = sx[q0.x & 0xFFFFF];
            float2 v1 = sx[q1.x & 0xFFFFF];
            float2 v2 = sx[q2.x & 0xFFFFF];
            float2 v3 = sx[q3.x & 0xFFFFF];
            float2 v4 = sx[q4.x & 0xFFFFF];
            float2 v5 = sx[q5.x & 0xFFFFF];
            float2 v6 = sx[q6.x & 0xFFFFF];
            float2 v7 = sx[q7.x & 0xFFFFF];
            int2 n0, n1, n2, n3, n4, n5, n6, n7;
            const bool nxt = (e + 16 <= eend);
            if (nxt) {  // prefetch next batch (overlaps compute)
                n0 = rec[e + 8];  n1 = rec[e + 9];  n2 = rec[e + 10]; n3 = rec[e + 11];
                n4 = rec[e + 12]; n5 = rec[e + 13]; n6 = rec[e + 14]; n7 = rec[e + 15];
            }
            PROC(q0, v0, a0) PROC(q1, v1, a1) PROC(q2, v2, a2) PROC(q3, v3, a3)
            PROC(q4, v4, a0) PROC(q5, v5, a1) PROC(q6, v6, a2) PROC(q7, v7, a3)
            e += 8;
            have = nxt;
            if (nxt) {
                q0 = n0; q1 = n1; q2 = n2; q3 = n3;
                q4 = n4; q5 = n5; q6 = n6; q7 = n7;
            }
        }
        for (; e < eend; ++e) {
            int2 qq = rec[e];
            float2 vv = sx[qq.x & 0xFFFFF];
            PROC(qq, vv, a0)
        }
        if (curn >= 0) aggh[(curn & 63) * AP + f] = (_Float16)((a0 + a1) + (a2 + a3));
#undef PROC
    }
    __syncthreads();

    // ---- MFMA: O[64,64] = [AGG | H1] @ [W2rel ; W2root], one 16-row tile per wave ----
    // (fragment layouts HW-verified in R9/R10/R11)
    const int lane = tid & 63;
    const int m16 = lane & 15;
    const int quad = lane >> 4;
    f32x4 acc[4];
    #pragma unroll
    for (int c_ = 0; c_ < 4; ++c_) acc[c_] = (f32x4){0.f, 0.f, 0.f, 0.f};

    const float2 sm = sxl[wv * 16 + m16];

    #pragma unroll
    for (int kt = 0; kt < 4; ++kt) {
        const int kk = kt * 32;
        half8 a0;
        if (kt < 2) {
            a0 = *(const half8*)&aggh[(wv * 16 + m16) * AP + kk + quad * 8];
        } else {
            const int fk0 = (kt - 2) * 32 + quad * 8;
            #pragma unroll
            for (int j = 0; j < 8; ++j) {
                const float wr = W1_rel[fk0 + j], wt = W1_root[fk0 + j], bb = b1[fk0 + j];
                a0[j] = (_Float16)fmaxf(0.f, fmaf(sm.x, wr, fmaf(sm.y, wt, bb)));
            }
        }
        #pragma unroll
        for (int ct = 0; ct < 4; ++ct) {
            const half8 bfrag = *(const half8*)&Bt[(ct * 16 + m16) * BPITCH + kk + quad * 8];
            acc[ct] = __builtin_amdgcn_mfma_f32_16x16x32_f16(a0, bfrag, acc[ct], 0, 0, 0);
        }
    }

    float b2c[4], w3rc[4], w3tc[4];
    #pragma unroll
    for (int ct = 0; ct < 4; ++ct) {
        const int col = ct * 16 + m16;
        b2c[ct] = b2[col]; w3rc[ct] = W3_rel[col]; w3tc[ct] = W3_root[col];
    }
    float pv[4] = {0.f, 0.f, 0.f, 0.f}, rv[4] = {0.f, 0.f, 0.f, 0.f};
    #pragma unroll
    for (int ct = 0; ct < 4; ++ct) {
        #pragma unroll
        for (int reg = 0; reg < 4; ++reg) {
            const float h2 = fmaxf(0.f, acc[ct][reg] + b2c[ct]);
            pv[reg] = fmaf(h2, w3rc[ct], pv[reg]);
            rv[reg] = fmaf(h2, w3tc[ct], rv[reg]);
        }
    }
    #pragma unroll
    for (int reg = 0; reg < 4; ++reg) {
        #pragma unroll
        for (int msk = 1; msk < 16; msk <<= 1) {
            pv[reg] += __shfl_xor(pv[reg], msk, 64);
            rv[reg] += __shfl_xor(rv[reg], msk, 64);
        }
    }
    if (m16 == 0) {
        #pragma unroll
        for (int reg = 0; reg < 4; ++reg) {
            const int gi = gi0 + wv * 16 + quad * 4 + reg;
            if (gi < NN) { p[gi] = pv[reg]; r[gi] = rv[reg]; }
        }
    }
}

// -------- bucketed output: out = seg_sum(w * p[src]) + r + b3 --------
__global__ __launch_bounds__(256) void k_out(const int* __restrict__ gbase,
                                             const int* __restrict__ ghist,
                                             const int2* __restrict__ rec,
                                             const float* __restrict__ pp,
                                             const float* __restrict__ rr,
                                             const float* __restrict__ b3,
                                             float* __restrict__ out) {
    __shared__ float loc[NPB];
    if (threadIdx.x < NPB) loc[threadIdx.x] = 0.f;
    __syncthreads();
    const int b = blockIdx.x;
    const int beg = gbase[b], cnt = ghist[b];
    for (int t = threadIdx.x; t < cnt; t += 256) {
        int2 rc = rec[beg + t];
        atomicAdd(&loc[rc.x >> 20], __int_as_float(rc.y) * pp[rc.x & 0xFFFFF]);
    }
    __syncthreads();
    int i = b * NPB + threadIdx.x;
    if (threadIdx.x < NPB && i < NN) out[i] = loc[threadIdx.x] + rr[i] + b3[0];
}

extern "C" void kernel_launch(void* const* d_in, const int* in_sizes, int n_in,
                              void* d_out, int out_size, void* d_ws, size_t ws_size,
                              hipStream_t stream) {
    const float* x       = (const float*)d_in[0];
    const int*   ei      = (const int*)  d_in[1];
    const float* ew      = (const float*)d_in[2];
    const float* W1_rel  = (const float*)d_in[3];
    const float* b1      = (const float*)d_in[4];
    const float* W1_root = (const float*)d_in[5];
    const float* W2_rel  = (const float*)d_in[6];
    const float* b2      = (const float*)d_in[7];
    const float* W2_root = (const float*)d_in[8];
    const float* W3_rel  = (const float*)d_in[9];
    const float* b3      = (const float*)d_in[10];
    const float* W3_root = (const float*)d_in[11];

    const int* src = ei;
    const int* dst = ei + NE;

    int2*   rec   = (int2*)d_ws;
    float2* sx    = (float2*)((int*)d_ws + 2 * (size_t)NE);
    float*  p     = (float*)(sx + NN);
    float*  r     = p + NN;
    int*    nbase = (int*)(r + NN);
    int*    nend  = nbase + NN;
    int*    ghist = nend + NN;
    int*    gbase = ghist + NB;
    int*    gcur  = gbase + NB;

    hipMemsetAsync(ghist, 0, NB * sizeof(int), stream);

    k_hist<<<NCH, 256, 0, stream>>>(dst, ghist);
    k_scan<<<1, 1024, 0, stream>>>(ghist, gbase, gcur);
    k_scatter<<<NCH, 256, 0, stream>>>(src, dst, ew, gcur, rec);
    k_sort<<<NB, 256, 0, stream>>>(gbase, ghist, rec, x, sx, nbase, nend);
    k_mega<<<NB2, 256, 0, stream>>>(nbase, nend, rec, sx,
                                    W1_rel, W1_root, b1,
                                    W2_rel, b2, W2_root,
                                    W3_rel, W3_root, p, r);
    k_out<<<NB, 256, 0, stream>>>(gbase, ghist, rec, p, r, b3, (float*)d_out);
}

// Round 13
// 351.177 us; speedup vs baseline: 4.4611x; 1.2044x over previous
//
#include <hip/hip_runtime.h>

#define NN 100000
#define NE 3200000
#define HID 64
#define NPB 128                         // nodes per bucket (dstlocal = dst & 127)
#define NB  ((NN + NPB - 1) / NPB)      // 782 buckets
#define CHUNK 4096                      // edges per hist/scatter workgroup
#define NCH ((NE + CHUNK - 1) / CHUNK)  // 782 chunks
#define CAP 5632                        // per-bucket record capacity (mean 4092, sd 64)
#define AP 72                           // f16 agg row pitch in halfs (144 B, 16B-aligned)
#define BPITCH 136                      // f16 Bt row pitch in halfs (272 B)

typedef _Float16 half8 __attribute__((ext_vector_type(8)));
typedef float f32x4 __attribute__((ext_vector_type(4)));

__device__ __forceinline__ float h2f(unsigned int u) {
    unsigned short s = (unsigned short)u;
    _Float16 h;
    __builtin_memcpy(&h, &s, 2);
    return (float)h;
}
__device__ __forceinline__ unsigned short f2hb(float v) {
    _Float16 h = (_Float16)v;
    unsigned short s;
    __builtin_memcpy(&s, &h, 2);
    return s;
}

// -------- global histogram over dst buckets --------
__global__ __launch_bounds__(256) void k_hist(const int* __restrict__ dst,
                                              int* __restrict__ ghist) {
    __shared__ int sh[NB];
    for (int j = threadIdx.x; j < NB; j += 256) sh[j] = 0;
    __syncthreads();
    const long long b0 = (long long)blockIdx.x * CHUNK;
    #pragma unroll
    for (int k = 0; k < CHUNK / 256; ++k) {
        long long e = b0 + k * 256 + threadIdx.x;
        if (e < NE) atomicAdd(&sh[dst[e] >> 7], 1);
    }
    __syncthreads();
    for (int j = threadIdx.x; j < NB; j += 256) {
        int c = sh[j];
        if (c) atomicAdd(&ghist[j], c);
    }
}

// -------- exclusive scan of NB bucket counts (single WG) --------
__global__ void k_scan(const int* __restrict__ ghist, int* __restrict__ gbase,
                       int* __restrict__ gcur) {
    __shared__ int sh[1024];
    const int tid = threadIdx.x;
    int v = (tid < NB) ? ghist[tid] : 0;
    sh[tid] = v;
    __syncthreads();
    #pragma unroll
    for (int off = 1; off < 1024; off <<= 1) {
        int t = (tid >= off) ? sh[tid - off] : 0;
        __syncthreads();
        sh[tid] += t;
        __syncthreads();
    }
    if (tid < NB) {
        int b = sh[tid] - v;
        gbase[tid] = b;
        gcur[tid] = b;
    }
}

// -------- bucketed scatter: LDS-staged, one reservation atomic per (WG,bucket) --------
__global__ __launch_bounds__(256) void k_scatter(const int* __restrict__ src,
                                                 const int* __restrict__ dst,
                                                 const float* __restrict__ ew,
                                                 int* __restrict__ gcur,
                                                 int2* __restrict__ rec) {
    __shared__ int sh_px[CHUNK];
    __shared__ int sh_w[CHUNK];
    __shared__ unsigned short sh_b[CHUNK];
    __shared__ int sh_cnt[NB];
    __shared__ int sh_base[NB];
    for (int j = threadIdx.x; j < NB; j += 256) sh_cnt[j] = 0;
    __syncthreads();
    const long long b0 = (long long)blockIdx.x * CHUNK;
    #pragma unroll
    for (int k = 0; k < CHUNK / 256; ++k) {
        int idx = k * 256 + threadIdx.x;
        long long e = b0 + idx;
        if (e < NE) {
            int d = dst[e];
            int b = d >> 7;
            sh_px[idx] = src[e] | ((d & 127) << 20);   // src < 2^20
            sh_w[idx] = __float_as_int(ew[e]);
            sh_b[idx] = (unsigned short)b;
            atomicAdd(&sh_cnt[b], 1);
        }
    }
    __syncthreads();
    for (int j = threadIdx.x; j < NB; j += 256) {
        int c = sh_cnt[j];
        sh_base[j] = c ? atomicAdd(&gcur[j], c) : 0;
        sh_cnt[j] = 0;                                  // reuse as running offset
    }
    __syncthreads();
    #pragma unroll
    for (int k = 0; k < CHUNK / 256; ++k) {
        int idx = k * 256 + threadIdx.x;
        long long e = b0 + idx;
        if (e < NE) {
            int b = sh_b[idx];
            int off = atomicAdd(&sh_cnt[b], 1);
            rec[sh_base[b] + off] = make_int2(sh_px[idx], sh_w[idx]);
        }
    }
}

// -------- per-bucket counting sort by dstlocal + fused s1 + sx table + node CSR --------
__global__ __launch_bounds__(256) void k_sort(const int* __restrict__ gbase,
                                              const int* __restrict__ ghist,
                                              int2* __restrict__ rec,
                                              const float* __restrict__ x,
                                              float2* __restrict__ sx,
                                              int* __restrict__ nbase,
                                              int* __restrict__ nend) {
    __shared__ int2 lrec[CAP];          // 44 KB
    __shared__ int hist[NPB];
    __shared__ int excl[NPB];
    __shared__ int cur[NPB];
    __shared__ float loc[NPB];
    const int tid = threadIdx.x;
    if (tid < NPB) { hist[tid] = 0; loc[tid] = 0.f; }
    __syncthreads();
    const int b = blockIdx.x;
    const int beg = gbase[b];
    const int cnt = min(ghist[b], CAP);
    for (int t = tid; t < cnt; t += 256) {
        int2 rc = rec[beg + t];
        lrec[t] = rc;
        int dl = rc.x >> 20;
        atomicAdd(&hist[dl], 1);
        atomicAdd(&loc[dl], __int_as_float(rc.y) * x[rc.x & 0xFFFFF]);  // s1 fused
    }
    __syncthreads();
    if (tid < NPB) excl[tid] = hist[tid];
    __syncthreads();
    #pragma unroll
    for (int off = 1; off < NPB; off <<= 1) {
        int t = (tid < NPB && tid >= off) ? excl[tid - off] : 0;
        __syncthreads();
        if (tid < NPB) excl[tid] += t;
        __syncthreads();
    }
    if (tid < NPB) {
        int e0 = excl[tid] - hist[tid];         // exclusive
        cur[tid] = e0;
        int i = b * NPB + tid;
        if (i < NN) {
            nbase[i] = beg + e0;
            nend[i]  = beg + e0 + hist[tid];
            sx[i] = make_float2(loc[tid], x[i]);   // packed (s1, x)
        }
    }
    __syncthreads();
    for (int t = tid; t < cnt; t += 256) {
        int2 rc = lrec[t];
        int pos = atomicAdd(&cur[rc.x >> 20], 1);
        rec[beg + pos] = rc;                    // scatter within hot 32 KB window
    }
}

// -------- prep: per-lane pre-gather. rec2[e] = (f16(w*s1), f16(w*x) | f16(w), dl) --------
// valid since ew >= 0: w*relu(z) == relu(w*z)
__global__ __launch_bounds__(256) void k_prep(const int2* __restrict__ rec,
                                              const float2* __restrict__ sx,
                                              int2* __restrict__ rec2) {
    const int e = blockIdx.x * 256 + threadIdx.x;   // NE % 256 == 0
    int2 rc = rec[e];
    const int s = rc.x & 0xFFFFF;
    const int dl = rc.x >> 20;                      // 0..127, window-local
    const float w = __int_as_float(rc.y);
    const float2 v = sx[s];
    rec2[e] = make_int2((int)f2hb(w * v.x) | ((int)f2hb(w * v.y) << 16),
                        (int)f2hb(w) | (dl << 16));
}

// -------- mega: full bucket, 512 threads, gather-free streaming edge phase + MFMA ----
__global__ __launch_bounds__(512) void k_mega(
        const int* __restrict__ nbase, const int* __restrict__ nend,
        const int2* __restrict__ rec2, const float2* __restrict__ sx,
        const float* __restrict__ W1_rel, const float* __restrict__ W1_root,
        const float* __restrict__ b1,
        const float* __restrict__ W2_rel, const float* __restrict__ b2,
        const float* __restrict__ W2_root,
        const float* __restrict__ W3_rel, const float* __restrict__ W3_root,
        float* __restrict__ p, float* __restrict__ r) {
    __shared__ _Float16 aggh[NPB * AP];       // 18432 B
    __shared__ _Float16 Bt[HID * BPITCH];     // 17408 B, [n][k]: k<64 W2rel, k>=64 W2root
    __shared__ float2 sxl[NPB];               // 1024 B -> 36.9 KB, 4 blocks/CU, 32 waves
    const int tid = threadIdx.x;
    const int f = tid & 63;
    const int wv = tid >> 6;                  // 0..7
    const int gi0 = blockIdx.x * NPB;

    for (int j = tid; j < NPB * AP / 2; j += 512) ((int*)aggh)[j] = 0;
    for (int idx = tid; idx < HID * HID; idx += 512) {
        int k = idx >> 6, n = idx & 63;
        Bt[n * BPITCH + k]       = (_Float16)W2_rel[idx];
        Bt[n * BPITCH + HID + k] = (_Float16)W2_root[idx];
    }
    if (tid < NPB) {
        int gi = gi0 + tid;
        sxl[tid] = (gi < NN) ? sx[gi] : make_float2(0.f, 0.f);
    }
    const float w1r = W1_rel[f], w1t = W1_root[f], b1f = b1[f];
    __syncthreads();

    // ---- streaming edge phase: wave owns 16 contiguous nodes; zero gathers ----
    {
        const int first = gi0 + wv * 16;
        int e = 0, eend = 0;
        if (first < NN) {
            e = nbase[first];
            eend = nend[min(first + 15, NN - 1)];
        }
        int curn = -1;
        float a0 = 0.f, a1 = 0.f, a2 = 0.f, a3 = 0.f;

#define PROC(QQ, AA)                                                              \
        {                                                                         \
            const int dl_ = (QQ).y >> 16;                                         \
            if (dl_ != curn) {                                                    \
                if (curn >= 0) aggh[curn * AP + f] = (_Float16)((a0 + a1) + (a2 + a3)); \
                curn = dl_; a0 = a1 = a2 = a3 = 0.f;                              \
            }                                                                     \
            const float ws_ = h2f((QQ).x & 0xFFFF);                               \
            const float wx_ = h2f(((unsigned)(QQ).x) >> 16);                      \
            const float wf_ = h2f((QQ).y & 0xFFFF);                               \
            AA += fmaxf(0.f, fmaf(ws_, w1r, fmaf(wx_, w1t, wf_ * b1f)));          \
        }

        int2 q0, q1, q2, q3, q4, q5, q6, q7;
        bool have = (e + 8 <= eend);
        if (have) {
            q0 = rec2[e];     q1 = rec2[e + 1]; q2 = rec2[e + 2]; q3 = rec2[e + 3];
            q4 = rec2[e + 4]; q5 = rec2[e + 5]; q6 = rec2[e + 6]; q7 = rec2[e + 7];
        }
        while (have) {
            int2 n0, n1, n2, n3, n4, n5, n6, n7;
            const bool nxt = (e + 16 <= eend);
            if (nxt) {
                n0 = rec2[e + 8];  n1 = rec2[e + 9];  n2 = rec2[e + 10]; n3 = rec2[e + 11];
                n4 = rec2[e + 12]; n5 = rec2[e + 13]; n6 = rec2[e + 14]; n7 = rec2[e + 15];
            }
            PROC(q0, a0) PROC(q1, a1) PROC(q2, a2) PROC(q3, a3)
            PROC(q4, a0) PROC(q5, a1) PROC(q6, a2) PROC(q7, a3)
            e += 8;
            have = nxt;
            if (nxt) {
                q0 = n0; q1 = n1; q2 = n2; q3 = n3;
                q4 = n4; q5 = n5; q6 = n6; q7 = n7;
            }
        }
        for (; e < eend; ++e) {
            int2 qq = rec2[e];
            PROC(qq, a0)
        }
        if (curn >= 0) aggh[curn * AP + f] = (_Float16)((a0 + a1) + (a2 + a3));
#undef PROC
    }
    __syncthreads();

    // ---- MFMA: O[128,64] = [AGG | H1] @ [W2rel ; W2root], wave wv -> rows wv*16.. ----
    const int m16 = tid & 15;
    const int quad = (tid & 63) >> 4;
    f32x4 acc[4];
    #pragma unroll
    for (int c_ = 0; c_ < 4; ++c_) acc[c_] = (f32x4){0.f, 0.f, 0.f, 0.f};

    const float2 sm = sxl[wv * 16 + m16];

    #pragma unroll
    for (int kt = 0; kt < 4; ++kt) {
        const int kk = kt * 32;
        half8 a0;
        if (kt < 2) {
            a0 = *(const half8*)&aggh[(wv * 16 + m16) * AP + kk + quad * 8];
        } else {
            const int fk0 = (kt - 2) * 32 + quad * 8;
            #pragma unroll
            for (int j = 0; j < 8; ++j) {
                const float wr = W1_rel[fk0 + j], wt = W1_root[fk0 + j], bb = b1[fk0 + j];
                a0[j] = (_Float16)fmaxf(0.f, fmaf(sm.x, wr, fmaf(sm.y, wt, bb)));
            }
        }
        #pragma unroll
        for (int ct = 0; ct < 4; ++ct) {
            const half8 bfrag = *(const half8*)&Bt[(ct * 16 + m16) * BPITCH + kk + quad * 8];
            acc[ct] = __builtin_amdgcn_mfma_f32_16x16x32_f16(a0, bfrag, acc[ct], 0, 0, 0);
        }
    }

    float b2c[4], w3rc[4], w3tc[4];
    #pragma unroll
    for (int ct = 0; ct < 4; ++ct) {
        const int col = ct * 16 + m16;
        b2c[ct] = b2[col]; w3rc[ct] = W3_rel[col]; w3tc[ct] = W3_root[col];
    }
    float pv[4] = {0.f, 0.f, 0.f, 0.f}, rv[4] = {0.f, 0.f, 0.f, 0.f};
    #pragma unroll
    for (int ct = 0; ct < 4; ++ct) {
        #pragma unroll
        for (int reg = 0; reg < 4; ++reg) {
            const float h2 = fmaxf(0.f, acc[ct][reg] + b2c[ct]);
            pv[reg] = fmaf(h2, w3rc[ct], pv[reg]);
            rv[reg] = fmaf(h2, w3tc[ct], rv[reg]);
        }
    }
    #pragma unroll
    for (int reg = 0; reg < 4; ++reg) {
        #pragma unroll
        for (int msk = 1; msk < 16; msk <<= 1) {
            pv[reg] += __shfl_xor(pv[reg], msk, 64);
            rv[reg] += __shfl_xor(rv[reg], msk, 64);
        }
    }
    if (m16 == 0) {
        #pragma unroll
        for (int reg = 0; reg < 4; ++reg) {
            const int gi = gi0 + wv * 16 + quad * 4 + reg;
            if (gi < NN) { p[gi] = pv[reg]; r[gi] = rv[reg]; }
        }
    }
}

// -------- bucketed output: out = seg_sum(w * p[src]) + r + b3 --------
__global__ __launch_bounds__(256) void k_out(const int* __restrict__ gbase,
                                             const int* __restrict__ ghist,
                                             const int2* __restrict__ rec,
                                             const float* __restrict__ pp,
                                             const float* __restrict__ rr,
                                             const float* __restrict__ b3,
                                             float* __restrict__ out) {
    __shared__ float loc[NPB];
    if (threadIdx.x < NPB) loc[threadIdx.x] = 0.f;
    __syncthreads();
    const int b = blockIdx.x;
    const int beg = gbase[b], cnt = ghist[b];
    for (int t = threadIdx.x; t < cnt; t += 256) {
        int2 rc = rec[beg + t];
        atomicAdd(&loc[rc.x >> 20], __int_as_float(rc.y) * pp[rc.x & 0xFFFFF]);
    }
    __syncthreads();
    int i = b * NPB + threadIdx.x;
    if (threadIdx.x < NPB && i < NN) out[i] = loc[threadIdx.x] + rr[i] + b3[0];
}

// -------- fallback layer-3 (only if ws too small for rec2): global atomics --------
__global__ void k_final_atomic(const int* __restrict__ src, const int* __restrict__ dst,
                               const float* __restrict__ ew, const float* __restrict__ pp,
                               float* __restrict__ s3) {
    int e = blockIdx.x * blockDim.x + threadIdx.x;
    if (e < NE) atomicAdd(&s3[dst[e]], ew[e] * pp[src[e]]);
}
__global__ void k_finalize(const float* __restrict__ s3, const float* __restrict__ rr,
                           const float* __restrict__ b3, float* __restrict__ out) {
    int i = blockIdx.x * blockDim.x + threadIdx.x;
    if (i < NN) out[i] = s3[i] + rr[i] + b3[0];
}

extern "C" void kernel_launch(void* const* d_in, const int* in_sizes, int n_in,
                              void* d_out, int out_size, void* d_ws, size_t ws_size,
                              hipStream_t stream) {
    const float* x       = (const float*)d_in[0];
    const int*   ei      = (const int*)  d_in[1];
    const float* ew      = (const float*)d_in[2];
    const float* W1_rel  = (const float*)d_in[3];
    const float* b1      = (const float*)d_in[4];
    const float* W1_root = (const float*)d_in[5];
    const float* W2_rel  = (const float*)d_in[6];
    const float* b2      = (const float*)d_in[7];
    const float* W2_root = (const float*)d_in[8];
    const float* W3_rel  = (const float*)d_in[9];
    const float* b3      = (const float*)d_in[10];
    const float* W3_root = (const float*)d_in[11];

    const int* src = ei;
    const int* dst = ei + NE;

    int2*   rec   = (int2*)d_ws;
    float2* sx    = (float2*)((int*)d_ws + 2 * (size_t)NE);
    float*  p     = (float*)(sx + NN);
    float*  r     = p + NN;
    int*    nbase = (int*)(r + NN);
    int*    nend  = nbase + NN;
    int*    ghist = nend + NN;
    int*    gbase = ghist + NB;
    int*    gcur  = gbase + NB;
    int*    tail  = gcur + NB;
    // rec2 after tail, 8B-aligned
    size_t  off   = ((size_t)((char*)tail - (char*)d_ws) + 7) & ~(size_t)7;
    int2*   rec2  = (int2*)((char*)d_ws + off);
    const size_t needed = off + (size_t)NE * 8;
    const bool big = (ws_size >= needed);
    if (!big) rec2 = rec;                     // in-place pack (per-thread same index)

    hipMemsetAsync(ghist, 0, NB * sizeof(int), stream);

    k_hist<<<NCH, 256, 0, stream>>>(dst, ghist);
    k_scan<<<1, 1024, 0, stream>>>(ghist, gbase, gcur);
    k_scatter<<<NCH, 256, 0, stream>>>(src, dst, ew, gcur, rec);
    k_sort<<<NB, 256, 0, stream>>>(gbase, ghist, rec, x, sx, nbase, nend);
    k_prep<<<NE / 256, 256, 0, stream>>>(rec, sx, rec2);
    k_mega<<<NB, 512, 0, stream>>>(nbase, nend, rec2, sx,
                                   W1_rel, W1_root, b1,
                                   W2_rel, b2, W2_root,
                                   W3_rel, W3_root, p, r);
    if (big) {
        k_out<<<NB, 256, 0, stream>>>(gbase, ghist, rec, p, r, b3, (float*)d_out);
    } else {
        float* s3 = (float*)nbase;            // dead after k_mega
        hipMemsetAsync(s3, 0, (size_t)NN * sizeof(float), stream);
        k_final_atomic<<<(NE + 255) / 256, 256, 0, stream>>>(src, dst, ew, p, s3);
        k_finalize<<<(NN + 255) / 256, 256, 0, stream>>>(s3, r, b3, (float*)d_out);
    }
}